// Round 3
// baseline (58572.290 us; speedup 1.0000x reference)
//
#include <hip/hip_runtime.h>
#include <math.h>
#include <stdint.h>

#define Bn 256
#define Tn 256
#define Dn 512
#define UNITSn 1024
#define NCn 512
#define G4n 4096
#define KTn 1536   // 512 (x) + 1024 (h)
#define NT 48      // K tiles of 32

typedef unsigned long long u64;
typedef __attribute__((ext_vector_type(4))) double d4;

__device__ __forceinline__ double hsigd(double z) {
    return fmin(fmax(0.2 * z + 0.5, 0.0), 1.0);
}

// pack logit+col into u64: fixed-point (logit+2048)*2^40 (<<10) | (1023-col)
__device__ __forceinline__ u64 packlc(double v, int col) {
    double s = (v + 2048.0) * 1099511627776.0;   // 2^40
    u64 q = (u64)s;                              // < 2^53
    return (q << 10) | (u64)(1023 - col);
}

// device-wide barrier, cache-op-minimal (proven round 2):
//   release fetch_add (ONE wbl2) by thread 0 only,
//   RELAXED polling (no per-poll invalidation),
//   ONE acquire load (single inv) after exit.
__device__ __forceinline__ void gbar(u64* bar, u64 target) {
    __syncthreads();
    if (threadIdx.x == 0) {
        __hip_atomic_fetch_add(bar, 1ull, __ATOMIC_RELEASE, __HIP_MEMORY_SCOPE_AGENT);
        int n = 0;
        while (__hip_atomic_load(bar, __ATOMIC_RELAXED, __HIP_MEMORY_SCOPE_AGENT) < target) {
            __builtin_amdgcn_s_sleep(1);
            if (++n > 50000) break;  // failsafe: corrupt, never hang
        }
        (void)__hip_atomic_load(bar, __ATOMIC_ACQUIRE, __HIP_MEMORY_SCOPE_AGENT);
    }
    __syncthreads();
}

// ---------------- persistent kernel: whole T loop, MFMA GEMM + fused logits ----------
// Grid 512 blocks x 256 thr, 2 blocks/CU co-resident (verified r1/r2: Occ 24.8%).
// B operand read as FP32 directly from W/U (per-XCD slice 3MB -> L2-resident across
// steps), converted to f64 in registers at staging. 2-deep register prefetch.
// AS_STR/BS_STR = 33 (odd) -> conflict-free quarter-wave A reads.
#define AS_STR 33   // doubles per A row
#define BS_STR 33   // doubles per B k-row
#define AS_TILE (64 * AS_STR)    // 2112
#define BS_TILE (32 * BS_STR)    // 1056

__global__ __launch_bounds__(256, 2) void lstm_persistent(
    const float* __restrict__ x,
    const float* __restrict__ W, const float* __restrict__ U,
    const float* __restrict__ bias,
    const float* __restrict__ Wout, const float* __restrict__ bout,
    double* __restrict__ h0buf, double* __restrict__ h1buf,
    u64* __restrict__ slots0, u64* __restrict__ slots1,
    u64* __restrict__ bar, int* __restrict__ out)
{
    // As0=0, As1=2112, Bs0=4224, Bs1=5280; total 6336 doubles = 50688 B.
    // zex[64][33] = 2112 doubles aliases As0 after the final GEMM barrier.
    __shared__ __align__(16) double smem[2 * AS_TILE + 2 * BS_TILE];

    const int tid = threadIdx.x;
    const int bid = blockIdx.x;
    const int ct_ = bid & 127;         // col tile: 8 units
    const int yt = bid >> 7;           // row tile: 64 rows
    const int u0 = ct_ * 8;
    const int rowbase = yt * 64;

    // ---- staging maps (phase 1) ----
    const int sr = tid >> 2;                // A: row 0..63
    const int sk0 = (tid & 3) * 8;          // A: k base 0,8,16,24
    const int lb_k = tid >> 3;              // B: k 0..31
    const int lb_c4 = (tid & 7) * 4;        // B: col base 0,4,...,28
    const int lb_gate = lb_c4 >> 3;
    const int lb_uoff = lb_c4 & 7;          // 0 or 4
    const int lb_coff = lb_gate * UNITSn + u0 + lb_uoff;

    // ---- MFMA lane mapping ----
    const int lane = tid & 63;
    const int rs = (tid >> 6) * 16;    // row strip base
    const int ml = lane & 15;          // m / n within tile
    const int kl = lane >> 4;          // k within quad

    // ---- self-calibrate C/D layout (once) ----
    d4 zero4 = {0.0, 0.0, 0.0, 0.0};
    double onek0 = (kl == 0) ? 1.0 : 0.0;
    double mk0   = (kl == 0) ? (double)ml : 0.0;
    d4 prow = __builtin_amdgcn_mfma_f64_16x16x4f64(mk0, onek0, zero4, 0, 0, 0);
    d4 pcol = __builtin_amdgcn_mfma_f64_16x16x4f64(onek0, mk0, zero4, 0, 0, 0);
    int zoff[4];
    #pragma unroll
    for (int r = 0; r < 4; r++)
        zoff[r] = (rs + (int)prow[r]) * 33 + (int)pcol[r];

    // ---- epilogue maps (hoisted) ----
    const int eu = tid & 7;
    const int rr = tid >> 3;           // 0..31
    const int ug = u0 + eu;
    const double bi0 = (double)bias[ug];
    const double bf0 = (double)bias[UNITSn + ug];
    const double bc0 = (double)bias[2 * UNITSn + ug];
    const double bo0 = (double)bias[3 * UNITSn + ug];
    double creg[2] = {0.0, 0.0};       // cell state lives in registers

    // ---- phase-2 maps (hoisted): 512 blocks = 32 rowT(8) x 16 colT(32) ----
    const int p2row = ((bid >> 4) << 3) + (tid >> 5);   // 0..255
    const int p2col = ((bid & 15) << 5) + (tid & 31);   // 0..511
    const float* wcol = Wout + p2col;
    const double bo2 = (double)bout[p2col];

    u64 bar_t = 0;

    for (int t = 0; t < Tn; t++) {
        const double* hin = (t & 1) ? h1buf : h0buf;
        double* hout      = (t & 1) ? h0buf : h1buf;
        const u64* sprev  = (t & 1) ? slots0 : slots1;   // filled by phase2(t-1)
        u64* scur         = (t & 1) ? slots1 : slots0;   // filled by phase2(t)

        if (ct_ == 0 && tid < 64) scur[rowbase + tid] = 0ull;

        const float* xrow = x + (size_t)(rowbase + sr) * (Tn * Dn) + (size_t)t * Dn;
        const double* hrow = hin + (size_t)(rowbase + sr) * UNITSn;

        // two named register stages (no runtime indexing -> no scratch)
        double apfE[8]; float4 bpfE;
        double apfO[8]; float4 bpfO;

        auto prefetch = [&](int it, double (&apf)[8], float4& bpf) {
            int k0 = it * 32 + sk0;
            if (k0 < Dn) {
                float4 v0 = *(const float4*)(xrow + k0);
                float4 v1 = *(const float4*)(xrow + k0 + 4);
                apf[0] = (double)v0.x; apf[1] = (double)v0.y;
                apf[2] = (double)v0.z; apf[3] = (double)v0.w;
                apf[4] = (double)v1.x; apf[5] = (double)v1.y;
                apf[6] = (double)v1.z; apf[7] = (double)v1.w;
            } else {
                const double* hp = hrow + (k0 - Dn);
                double2 a = *(const double2*)(hp + 0);
                double2 b = *(const double2*)(hp + 2);
                double2 c2 = *(const double2*)(hp + 4);
                double2 d = *(const double2*)(hp + 6);
                apf[0] = a.x; apf[1] = a.y; apf[2] = b.x; apf[3] = b.y;
                apf[4] = c2.x; apf[5] = c2.y; apf[6] = d.x; apf[7] = d.y;
            }
            int kB = it * 32 + lb_k;
            const float* rowp = (kB < Dn) ? (W + (size_t)kB * G4n)
                                          : (U + (size_t)(kB - Dn) * G4n);
            bpf = *(const float4*)(rowp + lb_coff);
        };
        auto store_tiles = [&](int p, const double (&apf)[8], const float4& bpf) {
            double* As = smem + p * AS_TILE;
            double* Bs = smem + 2 * AS_TILE + p * BS_TILE;
            #pragma unroll
            for (int j = 0; j < 8; j += 2) {
                double2 w2; w2.x = apf[j]; w2.y = apf[j + 1];
                *(double2*)&As[sr * AS_STR + sk0 + j] = w2;
            }
            double2 w0; w0.x = (double)bpf.x; w0.y = (double)bpf.y;
            double2 w1; w1.x = (double)bpf.z; w1.y = (double)bpf.w;
            *(double2*)&Bs[lb_k * BS_STR + lb_c4] = w0;
            *(double2*)&Bs[lb_k * BS_STR + lb_c4 + 2] = w1;
        };

        d4 acc[2];
        acc[0] = zero4; acc[1] = zero4;

        auto do_mfma = [&](int p) {
            const double* As = smem + p * AS_TILE;
            const double* Bs = smem + 2 * AS_TILE + p * BS_TILE;
            #pragma unroll
            for (int kq = 0; kq < 8; kq++) {
                double a = As[(rs + ml) * AS_STR + kq * 4 + kl];
                double b0 = Bs[(kq * 4 + kl) * BS_STR + ml];
                double b1 = Bs[(kq * 4 + kl) * BS_STR + 16 + ml];
                acc[0] = __builtin_amdgcn_mfma_f64_16x16x4f64(a, b0, acc[0], 0, 0, 0);
                acc[1] = __builtin_amdgcn_mfma_f64_16x16x4f64(a, b1, acc[1], 0, 0, 0);
            }
        };

        // ---- 2-deep pipelined K loop: even its in LDS buf0, odd in buf1 ----
        prefetch(0, apfE, bpfE);
        prefetch(1, apfO, bpfO);
        store_tiles(0, apfE, bpfE);
        __syncthreads();

        for (int itp = 0; itp < NT; itp += 2) {
            // sub-iter even: it = itp (buf0)
            if (itp + 2 < NT) prefetch(itp + 2, apfE, bpfE);
            do_mfma(0);
            store_tiles(1, apfO, bpfO);          // it = itp+1 -> buf1
            __syncthreads();
            // sub-iter odd: it = itp+1 (buf1)
            if (itp + 3 < NT) prefetch(itp + 3, apfO, bpfO);
            do_mfma(1);
            if (itp + 2 < NT) store_tiles(0, apfE, bpfE);  // it = itp+2 -> buf0
            __syncthreads();
        }

        // ---- gate exchange: zex[64][33] aliases As0 (post-final-barrier) ----
        double* zex = smem;
        #pragma unroll
        for (int r = 0; r < 4; r++) {
            zex[zoff[r]] = acc[0][r];
            zex[zoff[r] + 16] = acc[1][r];
        }
        __syncthreads();

        // ---- epilogue: 2 cells/thread (rows rr, rr+32; unit eu) ----
        #pragma unroll
        for (int s = 0; s < 2; s++) {
            int r = rr + 32 * s;
            int row = rowbase + r;
            double zi = zex[r * 33 + eu]      + bi0;
            double zf = zex[r * 33 + 8 + eu]  + bf0;
            double zc = zex[r * 33 + 16 + eu] + bc0;
            double zo = zex[r * 33 + 24 + eu] + bo0;
            if (t > 0) {
                u64 sp = sprev[row];
                int idx = 1023 - (int)(sp & 1023ull);
                const float* wrow = W + (size_t)(Dn + idx) * G4n + ug;
                zi += (double)wrow[0];
                zf += (double)wrow[UNITSn];
                zc += (double)wrow[2 * UNITSn];
                zo += (double)wrow[3 * UNITSn];
                if (ct_ == 0 && eu == 0) out[(size_t)row * Tn + (t - 1)] = idx;
            }
            double cold = creg[s];
            double ig = hsigd(zi), fg = hsigd(zf), og = hsigd(zo);
            double cn = fg * cold + ig * tanh(zc);
            double hn = og * tanh(cn);
            creg[s] = cn;
            hout[(size_t)row * UNITSn + ug] = hn;
        }

        gbar(bar, bar_t += 512);        // h(t) globally visible

        // ---- phase 2: logits + argmax, all 512 blocks, 4-way ILP fp64 dot ----
        {
            const double* hr = hout + (size_t)p2row * UNITSn;
            double a0 = 0.0, a1 = 0.0, a2 = 0.0, a3 = 0.0;
            #pragma unroll 2
            for (int k = 0; k < UNITSn; k += 4) {
                double2 h01 = *(const double2*)(hr + k);
                double2 h23 = *(const double2*)(hr + k + 2);
                a0 = fma(h01.x, (double)wcol[(size_t)k * NCn], a0);
                a1 = fma(h01.y, (double)wcol[(size_t)(k + 1) * NCn], a1);
                a2 = fma(h23.x, (double)wcol[(size_t)(k + 2) * NCn], a2);
                a3 = fma(h23.y, (double)wcol[(size_t)(k + 3) * NCn], a3);
            }
            double a = (a0 + a1) + (a2 + a3);
            u64 best = packlc(a + bo2, p2col);
            #pragma unroll
            for (int m = 16; m >= 1; m >>= 1) {
                u64 o = __shfl_xor(best, m, 64);
                if (o > best) best = o;
            }
            if ((tid & 31) == 0) atomicMax(&scur[p2row], best);
        }

        gbar(bar, bar_t += 512);        // slots(t) globally visible
    }

    // t = T-1 = 255 (odd) -> its slots live in slots1
    if (bid == 0) {
        u64 s = slots1[tid];
        out[(size_t)tid * Tn + (Tn - 1)] = 1023 - (int)(s & 1023ull);
    }
}

// ---------------- fallback path (small workspace): round-4 proven kernels --------
__global__ __launch_bounds__(256, 2) void lstm_step(
    const float* __restrict__ x, const float* __restrict__ W,
    const float* __restrict__ U, const float* __restrict__ bias,
    const double* __restrict__ hin, double* __restrict__ hout,
    double* __restrict__ cst,
    const u64* __restrict__ slots_prev, u64* __restrict__ slots_cur,
    int* __restrict__ out, int t)
{
    __shared__ __align__(16) double smem[6144];

    const int tid = threadIdx.x;
    const int bid = blockIdx.x;
    const int ut = bid & 127;
    const int yt = bid >> 7;
    const int u0 = ut * 8;
    const int rowbase = yt * 64;

    if (ut == 0 && tid < 64) slots_cur[rowbase + tid] = 0ull;

    const int la_row = tid >> 2;
    const int la_k0 = (tid & 3) * 8;
    const int lb_k  = tid >> 3;
    const int lb_c4 = (tid & 7) * 4;
    const int lb_gate = lb_c4 >> 3;
    const int lb_uoff = lb_c4 & 7;

    const float* xrow = x + (size_t)(rowbase + la_row) * (Tn * Dn) + (size_t)t * Dn;
    const double* hrow = hin + (size_t)(rowbase + la_row) * UNITSn;

    double a_pf[8];
    double b_pf[4];

    auto prefetch = [&](int it) {
        int kg = it * 32;
        int k0 = kg + la_k0;
        if (k0 < Dn) {
            float4 v0 = *(const float4*)(xrow + k0);
            float4 v1 = *(const float4*)(xrow + k0 + 4);
            a_pf[0] = (double)v0.x; a_pf[1] = (double)v0.y;
            a_pf[2] = (double)v0.z; a_pf[3] = (double)v0.w;
            a_pf[4] = (double)v1.x; a_pf[5] = (double)v1.y;
            a_pf[6] = (double)v1.z; a_pf[7] = (double)v1.w;
        } else {
            const double* hp = hrow + (k0 - Dn);
            double2 h0v = *(const double2*)(hp + 0);
            double2 h1v = *(const double2*)(hp + 2);
            double2 h2v = *(const double2*)(hp + 4);
            double2 h3v = *(const double2*)(hp + 6);
            a_pf[0] = h0v.x; a_pf[1] = h0v.y; a_pf[2] = h1v.x; a_pf[3] = h1v.y;
            a_pf[4] = h2v.x; a_pf[5] = h2v.y; a_pf[6] = h3v.x; a_pf[7] = h3v.y;
        }
        int kB = kg + lb_k;
        const float* rowp = (kB < Dn) ? (W + (size_t)kB * G4n)
                                      : (U + (size_t)(kB - Dn) * G4n);
        float4 wv = *(const float4*)(rowp + lb_gate * UNITSn + u0 + lb_uoff);
        b_pf[0] = (double)wv.x; b_pf[1] = (double)wv.y;
        b_pf[2] = (double)wv.z; b_pf[3] = (double)wv.w;
    };
    auto store_tiles = [&](int p) {
        double* As = smem + p * 2048;
        double* Bs = smem + 4096 + p * 1024;
        #pragma unroll
        for (int j = 0; j < 8; j++) As[(la_k0 + j) * 64 + la_row] = a_pf[j];
        double2 w0; w0.x = b_pf[0]; w0.y = b_pf[1];
        double2 w1; w1.x = b_pf[2]; w1.y = b_pf[3];
        *(double2*)&Bs[lb_k * 32 + lb_c4] = w0;
        *(double2*)&Bs[lb_k * 32 + lb_c4 + 2] = w1;
    };

    const int lane = tid & 63;
    const int wv_ = tid >> 6;
    const int ri = lane >> 3;
    const int cj = lane & 7;
    const int rb = wv_ * 16 + ri * 2;

    double acc[2][4];
    #pragma unroll
    for (int i = 0; i < 2; i++)
        #pragma unroll
        for (int j = 0; j < 4; j++) acc[i][j] = 0.0;

    prefetch(0);
    store_tiles(0);
    __syncthreads();

    int p = 0;
    for (int it = 0; it < NT; it++) {
        if (it + 1 < NT) prefetch(it + 1);
        {
            const double* As = smem + p * 2048;
            const double* Bs = smem + 4096 + p * 1024;
            #pragma unroll
            for (int k = 0; k < 32; k++) {
                double2 a2 = *(const double2*)&As[k * 64 + rb];
                double2 b0 = *(const double2*)&Bs[k * 32 + cj * 4];
                double2 b1 = *(const double2*)&Bs[k * 32 + cj * 4 + 2];
                acc[0][0] = fma(a2.x, b0.x, acc[0][0]);
                acc[0][1] = fma(a2.x, b0.y, acc[0][1]);
                acc[0][2] = fma(a2.x, b1.x, acc[0][2]);
                acc[0][3] = fma(a2.x, b1.y, acc[0][3]);
                acc[1][0] = fma(a2.y, b0.x, acc[1][0]);
                acc[1][1] = fma(a2.y, b0.y, acc[1][1]);
                acc[1][2] = fma(a2.y, b1.x, acc[1][2]);
                acc[1][3] = fma(a2.y, b1.y, acc[1][3]);
            }
        }
        if (it + 1 < NT) store_tiles(p ^ 1);
        __syncthreads();
        p ^= 1;
    }

    double* zex = smem;
    #pragma unroll
    for (int i = 0; i < 2; i++) {
        double2 z0; z0.x = acc[i][0]; z0.y = acc[i][1];
        double2 z1; z1.x = acc[i][2]; z1.y = acc[i][3];
        *(double2*)&zex[(rb + i) * 32 + cj * 4] = z0;
        *(double2*)&zex[(rb + i) * 32 + cj * 4 + 2] = z1;
    }
    __syncthreads();

    const int eu = tid & 7;
    const int rr = tid >> 3;
    const int ug = u0 + eu;
    const double bi0 = (double)bias[ug];
    const double bf0 = (double)bias[UNITSn + ug];
    const double bc0 = (double)bias[2 * UNITSn + ug];
    const double bo0 = (double)bias[3 * UNITSn + ug];

    #pragma unroll
    for (int s = 0; s < 2; s++) {
        int r = rr + 32 * s;
        int row = rowbase + r;
        double zi = zex[r * 32 + eu]      + bi0;
        double zf = zex[r * 32 + 8 + eu]  + bf0;
        double zc = zex[r * 32 + 16 + eu] + bc0;
        double zo = zex[r * 32 + 24 + eu] + bo0;
        if (t > 0) {
            u64 sp = slots_prev[row];
            int idx = 1023 - (int)(sp & 1023ull);
            const float* wrow = W + (size_t)(Dn + idx) * G4n + ug;
            zi += (double)wrow[0];
            zf += (double)wrow[UNITSn];
            zc += (double)wrow[2 * UNITSn];
            zo += (double)wrow[3 * UNITSn];
            if (ut == 0 && eu == 0) out[(size_t)row * Tn + (t - 1)] = idx;
        }
        size_t off = (size_t)row * UNITSn + ug;
        double cold = cst[off];
        double ig = hsigd(zi), fg = hsigd(zf), og = hsigd(zo);
        double cn = fg * cold + ig * tanh(zc);
        double hn = og * tanh(cn);
        cst[off] = cn;
        hout[off] = hn;
    }
}

#define C_RT 8
#define C_CT 64
#define C_KC 32

__global__ __launch_bounds__(256) void logits_argmax(
    const double* __restrict__ h, const float* __restrict__ Wout,
    const float* __restrict__ bout, u64* __restrict__ slots)
{
    __shared__ double Hs[C_KC][9];
    __shared__ float  Ws[C_KC][C_CT];

    const int tid = threadIdx.x;
    const int ty = tid >> 5;
    const int tx = tid & 31;
    const int rbase = blockIdx.y * C_RT;
    const int cbase = blockIdx.x * C_CT;

    double acc0 = 0.0, acc1 = 0.0;

    const int lh_row = tid >> 5;
    const int lh_kk = tid & 31;
    const int lw_kk = tid >> 4;
    const int lw_j0 = (tid & 15) * 4;

    for (int kb = 0; kb < UNITSn; kb += C_KC) {
        Hs[lh_kk][lh_row] = h[(size_t)(rbase + lh_row) * UNITSn + kb + lh_kk];
        #pragma unroll
        for (int it = 0; it < 2; it++) {
            int kk = lw_kk + it * 16;
            float4 v = *(const float4*)(Wout + (size_t)(kb + kk) * NCn + cbase + lw_j0);
            *(float4*)&Ws[kk][lw_j0] = v;
        }
        __syncthreads();
        #pragma unroll
        for (int kk = 0; kk < C_KC; kk++) {
            double a = Hs[kk][ty];
            float2 wv = *(const float2*)&Ws[kk][tx * 2];
            acc0 = fma(a, (double)wv.x, acc0);
            acc1 = fma(a, (double)wv.y, acc1);
        }
        __syncthreads();
    }

    int col0 = cbase + tx * 2;
    double lg0 = acc0 + (double)bout[col0];
    double lg1 = acc1 + (double)bout[col0 + 1];

    u64 p0 = packlc(lg0, col0);
    u64 p1 = packlc(lg1, col0 + 1);
    u64 best = (p0 > p1) ? p0 : p1;
    #pragma unroll
    for (int off = 16; off >= 1; off >>= 1) {
        u64 o = __shfl_down(best, off, 32);
        if (o > best) best = o;
    }
    if (tx == 0) atomicMax(&slots[rbase + ty], best);
}

__global__ void final_decode(const u64* __restrict__ slots, int* __restrict__ out) {
    int b = threadIdx.x;
    u64 s = slots[b];
    out[(size_t)b * Tn + (Tn - 1)] = 1023 - (int)(s & 1023ull);
}

extern "C" void kernel_launch(void* const* d_in, const int* in_sizes, int n_in,
                              void* d_out, int out_size, void* d_ws, size_t ws_size,
                              hipStream_t stream) {
    const float* x    = (const float*)d_in[0];
    const float* W    = (const float*)d_in[1];
    const float* U    = (const float*)d_in[2];
    const float* bias = (const float*)d_in[3];
    const float* Wout = (const float*)d_in[4];
    const float* bout = (const float*)d_in[5];
    int* out = (int*)d_out;
    char* ws = (char*)d_ws;

    // ws layout: h0 (2MB) | h1 (2MB) | c (2MB, fallback only) | slots0/1 (4KB) |
    //            bar (8B @ 6MB+4096)
    double* h0 = (double*)(ws);
    double* h1 = (double*)(ws + (2u << 20));
    double* c  = (double*)(ws + (4u << 20));
    u64* slots0 = (u64*)(ws + (6u << 20));
    u64* slots1 = (u64*)(ws + (6u << 20) + 2048);
    u64* bar    = (u64*)(ws + (6u << 20) + 4096);

    const size_t NEED = (7ull << 20);
    const bool big = ws_size >= NEED;

    hipMemsetAsync(d_ws, 0, (6u << 20) + 8192, stream);

    if (big) {
        lstm_persistent<<<dim3(512), 256, 0, stream>>>(x, W, U, bias, Wout, bout,
                                                       h0, h1, slots0, slots1, bar, out);
    } else {
        for (int t = 0; t < Tn; t++) {
            double* hin  = (t & 1) ? h1 : h0;
            double* hout = (t & 1) ? h0 : h1;
            u64* sprev = (t & 1) ? slots0 : slots1;
            u64* scur  = (t & 1) ? slots1 : slots0;
            lstm_step<<<dim3(512), 256, 0, stream>>>(x, W, U, bias, hin, hout, c,
                                                     sprev, scur, out, t);
            logits_argmax<<<dim3(8, 32), 256, 0, stream>>>(hout, Wout, bout, scur);
        }
        final_decode<<<1, Bn, 0, stream>>>(slots1, out);
    }
}

// Round 4
// 57213.385 us; speedup vs baseline: 1.0238x; 1.0238x over previous
//
#include <hip/hip_runtime.h>
#include <math.h>
#include <stdint.h>

#define Bn 256
#define Tn 256
#define Dn 512
#define UNITSn 1024
#define NCn 512
#define G4n 4096
#define KTn 1536   // 512 (x) + 1024 (h)
#define NT 48      // K tiles of 32

typedef unsigned long long u64;
typedef __attribute__((ext_vector_type(4))) double d4;

__device__ __forceinline__ double hsigd(double z) {
    return fmin(fmax(0.2 * z + 0.5, 0.0), 1.0);
}

// pack logit+col into u64: fixed-point (logit+2048)*2^40 (<<10) | (1023-col)
__device__ __forceinline__ u64 packlc(double v, int col) {
    double s = (v + 2048.0) * 1099511627776.0;   // 2^40
    u64 q = (u64)s;                              // < 2^53
    return (q << 10) | (u64)(1023 - col);
}

// In-loop barrier WITHOUT vmcnt drain: __syncthreads() emits
// "s_waitcnt vmcnt(0) lgkmcnt(0); s_barrier", which kills the register
// prefetch pipeline every iteration (the m97 barrier-drain stall). We only
// need LDS ordering here: each wave drains its own ds ops (lgkmcnt(0)),
// global prefetch loads stay in flight across the barrier; the compiler's
// own counted vmcnt waits cover register deps for the ds_writes.
#define BARLDS() asm volatile("s_waitcnt lgkmcnt(0)\n\ts_barrier" ::: "memory")

// device-wide barrier, cache-op-minimal (proven round 2):
//   release fetch_add (ONE wbl2) by thread 0 only,
//   RELAXED polling (no per-poll invalidation),
//   ONE acquire load (single inv) after exit.
__device__ __forceinline__ void gbar(u64* bar, u64 target) {
    __syncthreads();
    if (threadIdx.x == 0) {
        __hip_atomic_fetch_add(bar, 1ull, __ATOMIC_RELEASE, __HIP_MEMORY_SCOPE_AGENT);
        int n = 0;
        while (__hip_atomic_load(bar, __ATOMIC_RELAXED, __HIP_MEMORY_SCOPE_AGENT) < target) {
            __builtin_amdgcn_s_sleep(1);
            if (++n > 50000) break;  // failsafe: corrupt, never hang
        }
        (void)__hip_atomic_load(bar, __ATOMIC_ACQUIRE, __HIP_MEMORY_SCOPE_AGENT);
    }
    __syncthreads();
}

// ---------------- persistent kernel: whole T loop, MFMA GEMM + fused logits ----------
// Grid 512 blocks x 256 thr, 2 blocks/CU co-resident (verified r1-r3: Occ ~24.8%).
// B operand read as FP32 directly from W/U, converted to f64 at staging.
// 2-deep register prefetch, now REAL: in-loop barriers keep vm loads in flight.
// AS_STR/BS_STR = 33 (odd) -> conflict-free A reads (verified r3: conflicts -9x).
#define AS_STR 33   // doubles per A row
#define BS_STR 33   // doubles per B k-row
#define AS_TILE (64 * AS_STR)    // 2112
#define BS_TILE (32 * BS_STR)    // 1056

__global__ __launch_bounds__(256, 2) void lstm_persistent(
    const float* __restrict__ x,
    const float* __restrict__ W, const float* __restrict__ U,
    const float* __restrict__ bias,
    const float* __restrict__ Wout, const float* __restrict__ bout,
    double* __restrict__ h0buf, double* __restrict__ h1buf,
    u64* __restrict__ slots0, u64* __restrict__ slots1,
    u64* __restrict__ bar, int* __restrict__ out)
{
    // As0=0, As1=2112, Bs0=4224, Bs1=5280; total 6336 doubles = 50688 B.
    // zex[64][33] = 2112 doubles aliases As0 after the final GEMM barrier.
    __shared__ __align__(16) double smem[2 * AS_TILE + 2 * BS_TILE];

    const int tid = threadIdx.x;
    const int bid = blockIdx.x;
    const int ct_ = bid & 127;         // col tile: 8 units
    const int yt = bid >> 7;           // row tile: 64 rows
    const int u0 = ct_ * 8;
    const int rowbase = yt * 64;

    // ---- staging maps (phase 1) ----
    const int sr = tid >> 2;                // A: row 0..63
    const int sk0 = (tid & 3) * 8;          // A: k base 0,8,16,24
    const int lb_k = tid >> 3;              // B: k 0..31
    const int lb_c4 = (tid & 7) * 4;        // B: col base 0,4,...,28
    const int lb_gate = lb_c4 >> 3;
    const int lb_uoff = lb_c4 & 7;          // 0 or 4
    const int lb_coff = lb_gate * UNITSn + u0 + lb_uoff;

    // ---- MFMA lane mapping ----
    const int lane = tid & 63;
    const int rs = (tid >> 6) * 16;    // row strip base
    const int ml = lane & 15;          // m / n within tile
    const int kl = lane >> 4;          // k within quad

    // ---- self-calibrate C/D layout (once) ----
    d4 zero4 = {0.0, 0.0, 0.0, 0.0};
    double onek0 = (kl == 0) ? 1.0 : 0.0;
    double mk0   = (kl == 0) ? (double)ml : 0.0;
    d4 prow = __builtin_amdgcn_mfma_f64_16x16x4f64(mk0, onek0, zero4, 0, 0, 0);
    d4 pcol = __builtin_amdgcn_mfma_f64_16x16x4f64(onek0, mk0, zero4, 0, 0, 0);
    int zoff[4];
    #pragma unroll
    for (int r = 0; r < 4; r++)
        zoff[r] = (rs + (int)prow[r]) * 33 + (int)pcol[r];

    // ---- epilogue maps (hoisted) ----
    const int eu = tid & 7;
    const int rr = tid >> 3;           // 0..31
    const int ug = u0 + eu;
    const double bi0 = (double)bias[ug];
    const double bf0 = (double)bias[UNITSn + ug];
    const double bc0 = (double)bias[2 * UNITSn + ug];
    const double bo0 = (double)bias[3 * UNITSn + ug];
    double creg[2] = {0.0, 0.0};       // cell state lives in registers

    // ---- phase-2 maps (hoisted): 512 blocks = 32 rowT(8) x 16 colT(32) ----
    const int p2row = ((bid >> 4) << 3) + (tid >> 5);   // 0..255
    const int p2col = ((bid & 15) << 5) + (tid & 31);   // 0..511
    const float* wcol = Wout + p2col;
    const double bo2 = (double)bout[p2col];

    u64 bar_t = 0;

    for (int t = 0; t < Tn; t++) {
        const double* hin = (t & 1) ? h1buf : h0buf;
        double* hout      = (t & 1) ? h0buf : h1buf;
        const u64* sprev  = (t & 1) ? slots0 : slots1;   // filled by phase2(t-1)
        u64* scur         = (t & 1) ? slots1 : slots0;   // filled by phase2(t)

        if (ct_ == 0 && tid < 64) scur[rowbase + tid] = 0ull;

        const float* xrow = x + (size_t)(rowbase + sr) * (Tn * Dn) + (size_t)t * Dn;
        const double* hrow = hin + (size_t)(rowbase + sr) * UNITSn;

        // two named register stages (no runtime indexing -> no scratch)
        double apfE[8]; float4 bpfE;
        double apfO[8]; float4 bpfO;

        auto prefetch = [&](int it, double (&apf)[8], float4& bpf) {
            int k0 = it * 32 + sk0;
            if (k0 < Dn) {
                float4 v0 = *(const float4*)(xrow + k0);
                float4 v1 = *(const float4*)(xrow + k0 + 4);
                apf[0] = (double)v0.x; apf[1] = (double)v0.y;
                apf[2] = (double)v0.z; apf[3] = (double)v0.w;
                apf[4] = (double)v1.x; apf[5] = (double)v1.y;
                apf[6] = (double)v1.z; apf[7] = (double)v1.w;
            } else {
                const double* hp = hrow + (k0 - Dn);
                double2 a = *(const double2*)(hp + 0);
                double2 b = *(const double2*)(hp + 2);
                double2 c2 = *(const double2*)(hp + 4);
                double2 d = *(const double2*)(hp + 6);
                apf[0] = a.x; apf[1] = a.y; apf[2] = b.x; apf[3] = b.y;
                apf[4] = c2.x; apf[5] = c2.y; apf[6] = d.x; apf[7] = d.y;
            }
            int kB = it * 32 + lb_k;
            const float* rowp = (kB < Dn) ? (W + (size_t)kB * G4n)
                                          : (U + (size_t)(kB - Dn) * G4n);
            bpf = *(const float4*)(rowp + lb_coff);
        };
        auto store_tiles = [&](int p, const double (&apf)[8], const float4& bpf) {
            double* As = smem + p * AS_TILE;
            double* Bs = smem + 2 * AS_TILE + p * BS_TILE;
            #pragma unroll
            for (int j = 0; j < 8; j += 2) {
                double2 w2; w2.x = apf[j]; w2.y = apf[j + 1];
                *(double2*)&As[sr * AS_STR + sk0 + j] = w2;
            }
            double2 w0; w0.x = (double)bpf.x; w0.y = (double)bpf.y;
            double2 w1; w1.x = (double)bpf.z; w1.y = (double)bpf.w;
            *(double2*)&Bs[lb_k * BS_STR + lb_c4] = w0;
            *(double2*)&Bs[lb_k * BS_STR + lb_c4 + 2] = w1;
        };

        d4 acc[2];
        acc[0] = zero4; acc[1] = zero4;

        auto do_mfma = [&](int p) {
            const double* As = smem + p * AS_TILE;
            const double* Bs = smem + 2 * AS_TILE + p * BS_TILE;
            __builtin_amdgcn_s_setprio(1);
            #pragma unroll
            for (int kq = 0; kq < 8; kq++) {
                double a = As[(rs + ml) * AS_STR + kq * 4 + kl];
                double b0 = Bs[(kq * 4 + kl) * BS_STR + ml];
                double b1 = Bs[(kq * 4 + kl) * BS_STR + 16 + ml];
                acc[0] = __builtin_amdgcn_mfma_f64_16x16x4f64(a, b0, acc[0], 0, 0, 0);
                acc[1] = __builtin_amdgcn_mfma_f64_16x16x4f64(a, b1, acc[1], 0, 0, 0);
            }
            __builtin_amdgcn_s_setprio(0);
        };

        // ---- 2-deep pipelined K loop: even its in LDS buf0, odd in buf1 ----
        prefetch(0, apfE, bpfE);
        prefetch(1, apfO, bpfO);
        store_tiles(0, apfE, bpfE);
        BARLDS();                                 // keep prefetch(1) in flight

        for (int itp = 0; itp < NT; itp += 2) {
            // sub-iter even: it = itp (buf0)
            if (itp + 2 < NT) prefetch(itp + 2, apfE, bpfE);
            do_mfma(0);
            store_tiles(1, apfO, bpfO);          // it = itp+1 -> buf1
            BARLDS();
            // sub-iter odd: it = itp+1 (buf1)
            if (itp + 3 < NT) prefetch(itp + 3, apfO, bpfO);
            do_mfma(1);
            if (itp + 2 < NT) store_tiles(0, apfE, bpfE);  // it = itp+2 -> buf0
            BARLDS();
        }

        // ---- gate exchange: zex[64][33] aliases As0 (post-final-barrier) ----
        double* zex = smem;
        #pragma unroll
        for (int r = 0; r < 4; r++) {
            zex[zoff[r]] = acc[0][r];
            zex[zoff[r] + 16] = acc[1][r];
        }
        __syncthreads();

        // ---- epilogue: 2 cells/thread (rows rr, rr+32; unit eu) ----
        #pragma unroll
        for (int s = 0; s < 2; s++) {
            int r = rr + 32 * s;
            int row = rowbase + r;
            double zi = zex[r * 33 + eu]      + bi0;
            double zf = zex[r * 33 + 8 + eu]  + bf0;
            double zc = zex[r * 33 + 16 + eu] + bc0;
            double zo = zex[r * 33 + 24 + eu] + bo0;
            if (t > 0) {
                u64 sp = sprev[row];
                int idx = 1023 - (int)(sp & 1023ull);
                const float* wrow = W + (size_t)(Dn + idx) * G4n + ug;
                zi += (double)wrow[0];
                zf += (double)wrow[UNITSn];
                zc += (double)wrow[2 * UNITSn];
                zo += (double)wrow[3 * UNITSn];
                if (ct_ == 0 && eu == 0) out[(size_t)row * Tn + (t - 1)] = idx;
            }
            double cold = creg[s];
            double ig = hsigd(zi), fg = hsigd(zf), og = hsigd(zo);
            double cn = fg * cold + ig * tanh(zc);
            double hn = og * tanh(cn);
            creg[s] = cn;
            hout[(size_t)row * UNITSn + ug] = hn;
        }

        gbar(bar, bar_t += 512);        // h(t) globally visible

        // ---- phase 2: logits + argmax, all 512 blocks, 4-way ILP fp64 dot ----
        {
            const double* hr = hout + (size_t)p2row * UNITSn;
            double a0 = 0.0, a1 = 0.0, a2 = 0.0, a3 = 0.0;
            #pragma unroll 2
            for (int k = 0; k < UNITSn; k += 4) {
                double2 h01 = *(const double2*)(hr + k);
                double2 h23 = *(const double2*)(hr + k + 2);
                a0 = fma(h01.x, (double)wcol[(size_t)k * NCn], a0);
                a1 = fma(h01.y, (double)wcol[(size_t)(k + 1) * NCn], a1);
                a2 = fma(h23.x, (double)wcol[(size_t)(k + 2) * NCn], a2);
                a3 = fma(h23.y, (double)wcol[(size_t)(k + 3) * NCn], a3);
            }
            double a = (a0 + a1) + (a2 + a3);
            u64 best = packlc(a + bo2, p2col);
            #pragma unroll
            for (int m = 16; m >= 1; m >>= 1) {
                u64 o = __shfl_xor(best, m, 64);
                if (o > best) best = o;
            }
            if ((tid & 31) == 0) atomicMax(&scur[p2row], best);
        }

        gbar(bar, bar_t += 512);        // slots(t) globally visible
    }

    // t = T-1 = 255 (odd) -> its slots live in slots1
    if (bid == 0) {
        u64 s = slots1[tid];
        out[(size_t)tid * Tn + (Tn - 1)] = 1023 - (int)(s & 1023ull);
    }
}

// ---------------- fallback path (small workspace): round-4 proven kernels --------
__global__ __launch_bounds__(256, 2) void lstm_step(
    const float* __restrict__ x, const float* __restrict__ W,
    const float* __restrict__ U, const float* __restrict__ bias,
    const double* __restrict__ hin, double* __restrict__ hout,
    double* __restrict__ cst,
    const u64* __restrict__ slots_prev, u64* __restrict__ slots_cur,
    int* __restrict__ out, int t)
{
    __shared__ __align__(16) double smem[6144];

    const int tid = threadIdx.x;
    const int bid = blockIdx.x;
    const int ut = bid & 127;
    const int yt = bid >> 7;
    const int u0 = ut * 8;
    const int rowbase = yt * 64;

    if (ut == 0 && tid < 64) slots_cur[rowbase + tid] = 0ull;

    const int la_row = tid >> 2;
    const int la_k0 = (tid & 3) * 8;
    const int lb_k  = tid >> 3;
    const int lb_c4 = (tid & 7) * 4;
    const int lb_gate = lb_c4 >> 3;
    const int lb_uoff = lb_c4 & 7;

    const float* xrow = x + (size_t)(rowbase + la_row) * (Tn * Dn) + (size_t)t * Dn;
    const double* hrow = hin + (size_t)(rowbase + la_row) * UNITSn;

    double a_pf[8];
    double b_pf[4];

    auto prefetch = [&](int it) {
        int kg = it * 32;
        int k0 = kg + la_k0;
        if (k0 < Dn) {
            float4 v0 = *(const float4*)(xrow + k0);
            float4 v1 = *(const float4*)(xrow + k0 + 4);
            a_pf[0] = (double)v0.x; a_pf[1] = (double)v0.y;
            a_pf[2] = (double)v0.z; a_pf[3] = (double)v0.w;
            a_pf[4] = (double)v1.x; a_pf[5] = (double)v1.y;
            a_pf[6] = (double)v1.z; a_pf[7] = (double)v1.w;
        } else {
            const double* hp = hrow + (k0 - Dn);
            double2 h0v = *(const double2*)(hp + 0);
            double2 h1v = *(const double2*)(hp + 2);
            double2 h2v = *(const double2*)(hp + 4);
            double2 h3v = *(const double2*)(hp + 6);
            a_pf[0] = h0v.x; a_pf[1] = h0v.y; a_pf[2] = h1v.x; a_pf[3] = h1v.y;
            a_pf[4] = h2v.x; a_pf[5] = h2v.y; a_pf[6] = h3v.x; a_pf[7] = h3v.y;
        }
        int kB = kg + lb_k;
        const float* rowp = (kB < Dn) ? (W + (size_t)kB * G4n)
                                      : (U + (size_t)(kB - Dn) * G4n);
        float4 wv = *(const float4*)(rowp + lb_gate * UNITSn + u0 + lb_uoff);
        b_pf[0] = (double)wv.x; b_pf[1] = (double)wv.y;
        b_pf[2] = (double)wv.z; b_pf[3] = (double)wv.w;
    };
    auto store_tiles = [&](int p) {
        double* As = smem + p * 2048;
        double* Bs = smem + 4096 + p * 1024;
        #pragma unroll
        for (int j = 0; j < 8; j++) As[(la_k0 + j) * 64 + la_row] = a_pf[j];
        double2 w0; w0.x = b_pf[0]; w0.y = b_pf[1];
        double2 w1; w1.x = b_pf[2]; w1.y = b_pf[3];
        *(double2*)&Bs[lb_k * 32 + lb_c4] = w0;
        *(double2*)&Bs[lb_k * 32 + lb_c4 + 2] = w1;
    };

    const int lane = tid & 63;
    const int wv_ = tid >> 6;
    const int ri = lane >> 3;
    const int cj = lane & 7;
    const int rb = wv_ * 16 + ri * 2;

    double acc[2][4];
    #pragma unroll
    for (int i = 0; i < 2; i++)
        #pragma unroll
        for (int j = 0; j < 4; j++) acc[i][j] = 0.0;

    prefetch(0);
    store_tiles(0);
    __syncthreads();

    int p = 0;
    for (int it = 0; it < NT; it++) {
        if (it + 1 < NT) prefetch(it + 1);
        {
            const double* As = smem + p * 2048;
            const double* Bs = smem + 4096 + p * 1024;
            #pragma unroll
            for (int k = 0; k < 32; k++) {
                double2 a2 = *(const double2*)&As[k * 64 + rb];
                double2 b0 = *(const double2*)&Bs[k * 32 + cj * 4];
                double2 b1 = *(const double2*)&Bs[k * 32 + cj * 4 + 2];
                acc[0][0] = fma(a2.x, b0.x, acc[0][0]);
                acc[0][1] = fma(a2.x, b0.y, acc[0][1]);
                acc[0][2] = fma(a2.x, b1.x, acc[0][2]);
                acc[0][3] = fma(a2.x, b1.y, acc[0][3]);
                acc[1][0] = fma(a2.y, b0.x, acc[1][0]);
                acc[1][1] = fma(a2.y, b0.y, acc[1][1]);
                acc[1][2] = fma(a2.y, b1.x, acc[1][2]);
                acc[1][3] = fma(a2.y, b1.y, acc[1][3]);
            }
        }
        if (it + 1 < NT) store_tiles(p ^ 1);
        __syncthreads();
        p ^= 1;
    }

    double* zex = smem;
    #pragma unroll
    for (int i = 0; i < 2; i++) {
        double2 z0; z0.x = acc[i][0]; z0.y = acc[i][1];
        double2 z1; z1.x = acc[i][2]; z1.y = acc[i][3];
        *(double2*)&zex[(rb + i) * 32 + cj * 4] = z0;
        *(double2*)&zex[(rb + i) * 32 + cj * 4 + 2] = z1;
    }
    __syncthreads();

    const int eu = tid & 7;
    const int rr = tid >> 3;
    const int ug = u0 + eu;
    const double bi0 = (double)bias[ug];
    const double bf0 = (double)bias[UNITSn + ug];
    const double bc0 = (double)bias[2 * UNITSn + ug];
    const double bo0 = (double)bias[3 * UNITSn + ug];

    #pragma unroll
    for (int s = 0; s < 2; s++) {
        int r = rr + 32 * s;
        int row = rowbase + r;
        double zi = zex[r * 32 + eu]      + bi0;
        double zf = zex[r * 32 + 8 + eu]  + bf0;
        double zc = zex[r * 32 + 16 + eu] + bc0;
        double zo = zex[r * 32 + 24 + eu] + bo0;
        if (t > 0) {
            u64 sp = slots_prev[row];
            int idx = 1023 - (int)(sp & 1023ull);
            const float* wrow = W + (size_t)(Dn + idx) * G4n + ug;
            zi += (double)wrow[0];
            zf += (double)wrow[UNITSn];
            zc += (double)wrow[2 * UNITSn];
            zo += (double)wrow[3 * UNITSn];
            if (ut == 0 && eu == 0) out[(size_t)row * Tn + (t - 1)] = idx;
        }
        size_t off = (size_t)row * UNITSn + ug;
        double cold = cst[off];
        double ig = hsigd(zi), fg = hsigd(zf), og = hsigd(zo);
        double cn = fg * cold + ig * tanh(zc);
        double hn = og * tanh(cn);
        cst[off] = cn;
        hout[off] = hn;
    }
}

#define C_RT 8
#define C_CT 64
#define C_KC 32

__global__ __launch_bounds__(256) void logits_argmax(
    const double* __restrict__ h, const float* __restrict__ Wout,
    const float* __restrict__ bout, u64* __restrict__ slots)
{
    __shared__ double Hs[C_KC][9];
    __shared__ float  Ws[C_KC][C_CT];

    const int tid = threadIdx.x;
    const int ty = tid >> 5;
    const int tx = tid & 31;
    const int rbase = blockIdx.y * C_RT;
    const int cbase = blockIdx.x * C_CT;

    double acc0 = 0.0, acc1 = 0.0;

    const int lh_row = tid >> 5;
    const int lh_kk = tid & 31;
    const int lw_kk = tid >> 4;
    const int lw_j0 = (tid & 15) * 4;

    for (int kb = 0; kb < UNITSn; kb += C_KC) {
        Hs[lh_kk][lh_row] = h[(size_t)(rbase + lh_row) * UNITSn + kb + lh_kk];
        #pragma unroll
        for (int it = 0; it < 2; it++) {
            int kk = lw_kk + it * 16;
            float4 v = *(const float4*)(Wout + (size_t)(kb + kk) * NCn + cbase + lw_j0);
            *(float4*)&Ws[kk][lw_j0] = v;
        }
        __syncthreads();
        #pragma unroll
        for (int kk = 0; kk < C_KC; kk++) {
            double a = Hs[kk][ty];
            float2 wv = *(const float2*)&Ws[kk][tx * 2];
            acc0 = fma(a, (double)wv.x, acc0);
            acc1 = fma(a, (double)wv.y, acc1);
        }
        __syncthreads();
    }

    int col0 = cbase + tx * 2;
    double lg0 = acc0 + (double)bout[col0];
    double lg1 = acc1 + (double)bout[col0 + 1];

    u64 p0 = packlc(lg0, col0);
    u64 p1 = packlc(lg1, col0 + 1);
    u64 best = (p0 > p1) ? p0 : p1;
    #pragma unroll
    for (int off = 16; off >= 1; off >>= 1) {
        u64 o = __shfl_down(best, off, 32);
        if (o > best) best = o;
    }
    if (tx == 0) atomicMax(&slots[rbase + ty], best);
}

__global__ void final_decode(const u64* __restrict__ slots, int* __restrict__ out) {
    int b = threadIdx.x;
    u64 s = slots[b];
    out[(size_t)b * Tn + (Tn - 1)] = 1023 - (int)(s & 1023ull);
}

extern "C" void kernel_launch(void* const* d_in, const int* in_sizes, int n_in,
                              void* d_out, int out_size, void* d_ws, size_t ws_size,
                              hipStream_t stream) {
    const float* x    = (const float*)d_in[0];
    const float* W    = (const float*)d_in[1];
    const float* U    = (const float*)d_in[2];
    const float* bias = (const float*)d_in[3];
    const float* Wout = (const float*)d_in[4];
    const float* bout = (const float*)d_in[5];
    int* out = (int*)d_out;
    char* ws = (char*)d_ws;

    // ws layout: h0 (2MB) | h1 (2MB) | c (2MB, fallback only) | slots0/1 (4KB) |
    //            bar (8B @ 6MB+4096)
    double* h0 = (double*)(ws);
    double* h1 = (double*)(ws + (2u << 20));
    double* c  = (double*)(ws + (4u << 20));
    u64* slots0 = (u64*)(ws + (6u << 20));
    u64* slots1 = (u64*)(ws + (6u << 20) + 2048);
    u64* bar    = (u64*)(ws + (6u << 20) + 4096);

    const size_t NEED = (7ull << 20);
    const bool big = ws_size >= NEED;

    hipMemsetAsync(d_ws, 0, (6u << 20) + 8192, stream);

    if (big) {
        lstm_persistent<<<dim3(512), 256, 0, stream>>>(x, W, U, bias, Wout, bout,
                                                       h0, h1, slots0, slots1, bar, out);
    } else {
        for (int t = 0; t < Tn; t++) {
            double* hin  = (t & 1) ? h1 : h0;
            double* hout = (t & 1) ? h0 : h1;
            u64* sprev = (t & 1) ? slots0 : slots1;
            u64* scur  = (t & 1) ? slots1 : slots0;
            lstm_step<<<dim3(512), 256, 0, stream>>>(x, W, U, bias, hin, hout, c,
                                                     sprev, scur, out, t);
            logits_argmax<<<dim3(8, 32), 256, 0, stream>>>(hout, Wout, bout, scur);
        }
        final_decode<<<1, Bn, 0, stream>>>(slots1, out);
    }
}

// Round 6
// 44297.049 us; speedup vs baseline: 1.3223x; 1.2916x over previous
//
#include <hip/hip_runtime.h>
#include <math.h>
#include <stdint.h>

#define Bn 256
#define Tn 256
#define Dn 512
#define UNITSn 1024
#define NCn 512
#define G4n 4096
#define KTn 1536   // 512 (x) + 1024 (h)
#define NT 48      // K tiles of 32

typedef unsigned long long u64;
typedef __attribute__((ext_vector_type(4))) double d4;

__device__ __forceinline__ double hsigd(double z) {
    return fmin(fmax(0.2 * z + 0.5, 0.0), 1.0);
}

// pack logit+col into u64: fixed-point (logit+2048)*2^40 (<<10) | (1023-col)
__device__ __forceinline__ u64 packlc(double v, int col) {
    double s = (v + 2048.0) * 1099511627776.0;   // 2^40
    u64 q = (u64)s;                              // < 2^53
    return (q << 10) | (u64)(1023 - col);
}

// In-loop barrier WITHOUT vmcnt drain (r4, neutral but harmless).
#define BARLDS() asm volatile("s_waitcnt lgkmcnt(0)\n\ts_barrier" ::: "memory")

// ---- two-level device barrier: 64 padded leaves (8 blocks each) + 1 root ----
// Event ep is 1-indexed and monotonic. Leaf value after event ep = 8*ep,
// root = 64*ep. Contention per cacheline: 8 instead of 512.
//
// gbar_rel_acq: RELEASE on leaf add (wbl2 flushes this block's dirty h lines),
//               relaxed poll, single ACQUIRE load at exit (one L2 inv per step).
// gbar_plain:   no cache ops at all. Entry __syncthreads drains vmcnt, so the
//               preceding device-scope atomicMax ops are globally performed;
//               consumers read slots via agent-scope (L2-bypass) loads -> no inv.
__device__ __forceinline__ void gbar_rel_acq(u64* leaves, u64* root, int leaf, u64 ep) {
    __syncthreads();
    if (threadIdx.x == 0) {
        u64 o = __hip_atomic_fetch_add(&leaves[leaf * 16], 1ull,
                                       __ATOMIC_RELEASE, __HIP_MEMORY_SCOPE_AGENT);
        if (o == 8 * ep - 1)
            __hip_atomic_fetch_add(root, 1ull, __ATOMIC_RELEASE, __HIP_MEMORY_SCOPE_AGENT);
        int n = 0;
        while (__hip_atomic_load(root, __ATOMIC_RELAXED, __HIP_MEMORY_SCOPE_AGENT) < 64 * ep) {
            __builtin_amdgcn_s_sleep(2);
            if (++n > 50000) break;  // failsafe: corrupt, never hang
        }
        (void)__hip_atomic_load(root, __ATOMIC_ACQUIRE, __HIP_MEMORY_SCOPE_AGENT);
    }
    __syncthreads();
}
__device__ __forceinline__ void gbar_plain(u64* leaves, u64* root, int leaf, u64 ep) {
    __syncthreads();   // drains vmcnt: atomicMax globally performed before leaf add
    if (threadIdx.x == 0) {
        u64 o = __hip_atomic_fetch_add(&leaves[leaf * 16], 1ull,
                                       __ATOMIC_RELAXED, __HIP_MEMORY_SCOPE_AGENT);
        if (o == 8 * ep - 1)
            __hip_atomic_fetch_add(root, 1ull, __ATOMIC_RELAXED, __HIP_MEMORY_SCOPE_AGENT);
        int n = 0;
        while (__hip_atomic_load(root, __ATOMIC_RELAXED, __HIP_MEMORY_SCOPE_AGENT) < 64 * ep) {
            __builtin_amdgcn_s_sleep(2);
            if (++n > 50000) break;
        }
    }
    __syncthreads();
}

// ---------------- persistent kernel: whole T loop, MFMA GEMM + fused logits ----------
// Grid 512 x 256 thr, 2 blocks/CU co-resident (verified r1-r4). XCD-aware swizzle:
// dispatch round-robins XCDs by bid%8, so XCD x owns GEMM col-tiles [16x,16x+16)
// (B slice 3 MB < 4 MB L2, reused across all 48 K iters and refetched from L3 only
// once per step after the single gbar1 invalidate) and Wout col-tile x (256 KB).
#define AS_STR 33   // doubles per A row
#define BS_STR 33   // doubles per B k-row
#define AS_TILE (64 * AS_STR)    // 2112
#define BS_TILE (32 * BS_STR)    // 1056

__global__ __launch_bounds__(256, 2) void lstm_persistent(
    const float* __restrict__ x,
    const float* __restrict__ W, const float* __restrict__ U,
    const float* __restrict__ bias,
    const float* __restrict__ Wout, const float* __restrict__ bout,
    double* __restrict__ h0buf, double* __restrict__ h1buf,
    u64* __restrict__ slots0, u64* __restrict__ slots1,
    u64* __restrict__ root, u64* __restrict__ leaves, int* __restrict__ out)
{
    // As0=0, As1=2112, Bs0=4224, Bs1=5280; total 6336 doubles = 50688 B.
    // zex[64][33] aliases As0 after final GEMM barrier; phase2 Hs/Ws alias smem too.
    __shared__ __align__(16) double smem[2 * AS_TILE + 2 * BS_TILE];

    const int tid = threadIdx.x;
    const int bid = blockIdx.x;
    const int leaf = bid >> 3;

    // ---- phase-1 swizzled tile mapping ----
    const int x8 = bid & 7;            // XCD (dispatch round-robin)
    const int q  = bid >> 3;
    const int ct_ = x8 * 16 + (q & 15);    // col tile: 8 units, XCD-local range
    const int yt  = q >> 4;                // row tile: 64 rows
    const int u0 = ct_ * 8;
    const int rowbase = yt * 64;

    // ---- staging maps (phase 1) ----
    const int sr = tid >> 2;                // A: row 0..63
    const int sk0 = (tid & 3) * 8;          // A: k base 0,8,16,24
    const int lb_k = tid >> 3;              // B: k 0..31
    const int lb_c4 = (tid & 7) * 4;        // B: col base 0,4,...,28
    const int lb_gate = lb_c4 >> 3;
    const int lb_uoff = lb_c4 & 7;          // 0 or 4
    const int lb_coff = lb_gate * UNITSn + u0 + lb_uoff;

    // ---- MFMA lane mapping ----
    const int lane = tid & 63;
    const int rs = (tid >> 6) * 16;    // row strip base
    const int ml = lane & 15;          // m / n within tile
    const int kl = lane >> 4;          // k within quad

    // ---- self-calibrate C/D layout (once) ----
    d4 zero4 = {0.0, 0.0, 0.0, 0.0};
    double onek0 = (kl == 0) ? 1.0 : 0.0;
    double mk0   = (kl == 0) ? (double)ml : 0.0;
    d4 prow = __builtin_amdgcn_mfma_f64_16x16x4f64(mk0, onek0, zero4, 0, 0, 0);
    d4 pcol = __builtin_amdgcn_mfma_f64_16x16x4f64(onek0, mk0, zero4, 0, 0, 0);
    int zoff[4];
    #pragma unroll
    for (int r = 0; r < 4; r++)
        zoff[r] = (rs + (int)prow[r]) * 33 + (int)pcol[r];

    // ---- epilogue maps (hoisted) ----
    const int eu = tid & 7;
    const int rr = tid >> 3;           // 0..31
    const int ug = u0 + eu;
    const double bi0 = (double)bias[ug];
    const double bf0 = (double)bias[UNITSn + ug];
    const double bc0 = (double)bias[2 * UNITSn + ug];
    const double bo0 = (double)bias[3 * UNITSn + ug];
    double creg[2] = {0.0, 0.0};       // cell state lives in registers

    // ---- phase-2 maps: 512 blocks = 8 colT(64 cols, XCD-local) x 64 rowT(4 rows) ----
    const int p2cb = (bid & 7) * 64;       // col base (XCD-local Wout slice)
    const int p2rb = (bid >> 3) * 4;       // row base (4 rows)
    const int p2wv = tid >> 6;             // wave -> row p2rb+p2wv
    const int p2ln = tid & 63;             // lane -> col p2cb+p2ln
    const int p2hr = tid >> 5;             // h stage: row 0..7 (use <4)
    const int p2hk = tid & 31;             // h stage: k
    const int p2wk = tid >> 3;             // W stage: k 0..31
    const int p2wj = (tid & 7) * 8;        // W stage: col base

    u64 bar_t = 0;

    for (int t = 0; t < Tn; t++) {
        const double* hin = (t & 1) ? h1buf : h0buf;
        double* hout      = (t & 1) ? h0buf : h1buf;
        const u64* sprev  = (t & 1) ? slots0 : slots1;   // filled by phase2(t-1)
        u64* scur         = (t & 1) ? slots1 : slots0;   // filled by phase2(t)

        if (ct_ == 0 && tid < 64) scur[rowbase + tid] = 0ull;

        const float* xrow = x + (size_t)(rowbase + sr) * (Tn * Dn) + (size_t)t * Dn;
        const double* hrow = hin + (size_t)(rowbase + sr) * UNITSn;

        // two named register stages (no runtime indexing -> no scratch)
        double apfE[8]; float4 bpfE;
        double apfO[8]; float4 bpfO;

        auto prefetch = [&](int it, double (&apf)[8], float4& bpf) {
            int k0 = it * 32 + sk0;
            if (k0 < Dn) {
                float4 v0 = *(const float4*)(xrow + k0);
                float4 v1 = *(const float4*)(xrow + k0 + 4);
                apf[0] = (double)v0.x; apf[1] = (double)v0.y;
                apf[2] = (double)v0.z; apf[3] = (double)v0.w;
                apf[4] = (double)v1.x; apf[5] = (double)v1.y;
                apf[6] = (double)v1.z; apf[7] = (double)v1.w;
            } else {
                const double* hp = hrow + (k0 - Dn);
                double2 a = *(const double2*)(hp + 0);
                double2 b = *(const double2*)(hp + 2);
                double2 c2 = *(const double2*)(hp + 4);
                double2 d = *(const double2*)(hp + 6);
                apf[0] = a.x; apf[1] = a.y; apf[2] = b.x; apf[3] = b.y;
                apf[4] = c2.x; apf[5] = c2.y; apf[6] = d.x; apf[7] = d.y;
            }
            int kB = it * 32 + lb_k;
            const float* rowp = (kB < Dn) ? (W + (size_t)kB * G4n)
                                          : (U + (size_t)(kB - Dn) * G4n);
            bpf = *(const float4*)(rowp + lb_coff);
        };
        auto store_tiles = [&](int p, const double (&apf)[8], const float4& bpf) {
            double* As = smem + p * AS_TILE;
            double* Bs = smem + 2 * AS_TILE + p * BS_TILE;
            #pragma unroll
            for (int j = 0; j < 8; j += 2) {
                double2 w2; w2.x = apf[j]; w2.y = apf[j + 1];
                *(double2*)&As[sr * AS_STR + sk0 + j] = w2;
            }
            double2 w0; w0.x = (double)bpf.x; w0.y = (double)bpf.y;
            double2 w1; w1.x = (double)bpf.z; w1.y = (double)bpf.w;
            *(double2*)&Bs[lb_k * BS_STR + lb_c4] = w0;
            *(double2*)&Bs[lb_k * BS_STR + lb_c4 + 2] = w1;
        };

        d4 acc[2];
        acc[0] = zero4; acc[1] = zero4;

        auto do_mfma = [&](int p) {
            const double* As = smem + p * AS_TILE;
            const double* Bs = smem + 2 * AS_TILE + p * BS_TILE;
            __builtin_amdgcn_s_setprio(1);
            #pragma unroll
            for (int kq = 0; kq < 8; kq++) {
                double a = As[(rs + ml) * AS_STR + kq * 4 + kl];
                double b0 = Bs[(kq * 4 + kl) * BS_STR + ml];
                double b1 = Bs[(kq * 4 + kl) * BS_STR + 16 + ml];
                acc[0] = __builtin_amdgcn_mfma_f64_16x16x4f64(a, b0, acc[0], 0, 0, 0);
                acc[1] = __builtin_amdgcn_mfma_f64_16x16x4f64(a, b1, acc[1], 0, 0, 0);
            }
            __builtin_amdgcn_s_setprio(0);
        };

        // ---- 2-deep pipelined K loop ----
        prefetch(0, apfE, bpfE);
        prefetch(1, apfO, bpfO);
        store_tiles(0, apfE, bpfE);
        BARLDS();

        for (int itp = 0; itp < NT; itp += 2) {
            if (itp + 2 < NT) prefetch(itp + 2, apfE, bpfE);
            do_mfma(0);
            store_tiles(1, apfO, bpfO);
            BARLDS();
            if (itp + 3 < NT) prefetch(itp + 3, apfO, bpfO);
            do_mfma(1);
            if (itp + 2 < NT) store_tiles(0, apfE, bpfE);
            BARLDS();
        }

        // ---- gate exchange: zex[64][33] aliases As0 ----
        double* zex = smem;
        #pragma unroll
        for (int r = 0; r < 4; r++) {
            zex[zoff[r]] = acc[0][r];
            zex[zoff[r] + 16] = acc[1][r];
        }
        __syncthreads();

        // ---- epilogue: 2 cells/thread (rows rr, rr+32; unit eu) ----
        #pragma unroll
        for (int s = 0; s < 2; s++) {
            int r = rr + 32 * s;
            int row = rowbase + r;
            double zi = zex[r * 33 + eu]      + bi0;
            double zf = zex[r * 33 + 8 + eu]  + bf0;
            double zc = zex[r * 33 + 16 + eu] + bc0;
            double zo = zex[r * 33 + 24 + eu] + bo0;
            if (t > 0) {
                // slots live at the coherent point (device-scope atomics);
                // read agent-scope (L2-bypass) so no cache invalidate is needed.
                u64 sp = __hip_atomic_load((u64*)&sprev[row], __ATOMIC_RELAXED,
                                           __HIP_MEMORY_SCOPE_AGENT);
                int idx = 1023 - (int)(sp & 1023ull);
                const float* wrow = W + (size_t)(Dn + idx) * G4n + ug;
                zi += (double)wrow[0];
                zf += (double)wrow[UNITSn];
                zc += (double)wrow[2 * UNITSn];
                zo += (double)wrow[3 * UNITSn];
                if (ct_ == 0 && eu == 0) out[(size_t)row * Tn + (t - 1)] = idx;
            }
            double cold = creg[s];
            double ig = hsigd(zi), fg = hsigd(zf), og = hsigd(zo);
            double cn = fg * cold + ig * tanh(zc);
            double hn = og * tanh(cn);
            creg[s] = cn;
            hout[(size_t)row * UNITSn + ug] = hn;
        }

        gbar_rel_acq(leaves, root, leaf, ++bar_t);   // h(t) published; ONE inv/step

        // ---- phase 2: LDS-staged logits tile (4 rows x 64 cols) + wave argmax ----
        {
            double* Hs = smem;                        // [32][5] doubles
            float*  Ws = (float*)(smem + 32 * 5);     // [32][64] floats
            double a2 = 0.0;
            for (int kb = 0; kb < UNITSn; kb += 32) {
                if (tid < 128)
                    Hs[p2hk * 5 + p2hr] =
                        hout[(size_t)(p2rb + p2hr) * UNITSn + kb + p2hk];
                const float* wp = Wout + (size_t)(kb + p2wk) * NCn + p2cb + p2wj;
                *(float4*)&Ws[p2wk * 64 + p2wj]     = *(const float4*)(wp);
                *(float4*)&Ws[p2wk * 64 + p2wj + 4] = *(const float4*)(wp + 4);
                __syncthreads();
                #pragma unroll
                for (int kk = 0; kk < 32; kk++)
                    a2 = fma(Hs[kk * 5 + p2wv], (double)Ws[kk * 64 + p2ln], a2);
                __syncthreads();
            }
            double lg = a2 + (double)bout[p2cb + p2ln];
            u64 best = packlc(lg, p2cb + p2ln);
            #pragma unroll
            for (int m = 32; m >= 1; m >>= 1) {
                u64 o = __shfl_xor(best, m, 64);
                if (o > best) best = o;
            }
            if (p2ln == 0) atomicMax(&scur[p2rb + p2wv], best);
        }

        gbar_plain(leaves, root, leaf, ++bar_t);     // slots(t) performed; no cache ops
    }

    // t = T-1 = 255 (odd) -> its slots live in slots1; read L2-bypass.
    if (bid == 0) {
        u64 s = __hip_atomic_load((u64*)&slots1[tid], __ATOMIC_RELAXED,
                                  __HIP_MEMORY_SCOPE_AGENT);
        out[(size_t)tid * Tn + (Tn - 1)] = 1023 - (int)(s & 1023ull);
    }
}

// ---------------- fallback path (small workspace): proven multi-launch kernels ------
__global__ __launch_bounds__(256, 2) void lstm_step(
    const float* __restrict__ x, const float* __restrict__ W,
    const float* __restrict__ U, const float* __restrict__ bias,
    const double* __restrict__ hin, double* __restrict__ hout,
    double* __restrict__ cst,
    const u64* __restrict__ slots_prev, u64* __restrict__ slots_cur,
    int* __restrict__ out, int t)
{
    __shared__ __align__(16) double smem[6144];

    const int tid = threadIdx.x;
    const int bid = blockIdx.x;
    const int ut = bid & 127;
    const int yt = bid >> 7;
    const int u0 = ut * 8;
    const int rowbase = yt * 64;

    if (ut == 0 && tid < 64) slots_cur[rowbase + tid] = 0ull;

    const int la_row = tid >> 2;
    const int la_k0 = (tid & 3) * 8;
    const int lb_k  = tid >> 3;
    const int lb_c4 = (tid & 7) * 4;
    const int lb_gate = lb_c4 >> 3;
    const int lb_uoff = lb_c4 & 7;

    const float* xrow = x + (size_t)(rowbase + la_row) * (Tn * Dn) + (size_t)t * Dn;
    const double* hrow = hin + (size_t)(rowbase + la_row) * UNITSn;

    double a_pf[8];
    double b_pf[4];

    auto prefetch = [&](int it) {
        int kg = it * 32;
        int k0 = kg + la_k0;
        if (k0 < Dn) {
            float4 v0 = *(const float4*)(xrow + k0);
            float4 v1 = *(const float4*)(xrow + k0 + 4);
            a_pf[0] = (double)v0.x; a_pf[1] = (double)v0.y;
            a_pf[2] = (double)v0.z; a_pf[3] = (double)v0.w;
            a_pf[4] = (double)v1.x; a_pf[5] = (double)v1.y;
            a_pf[6] = (double)v1.z; a_pf[7] = (double)v1.w;
        } else {
            const double* hp = hrow + (k0 - Dn);
            double2 h0v = *(const double2*)(hp + 0);
            double2 h1v = *(const double2*)(hp + 2);
            double2 h2v = *(const double2*)(hp + 4);
            double2 h3v = *(const double2*)(hp + 6);
            a_pf[0] = h0v.x; a_pf[1] = h0v.y; a_pf[2] = h1v.x; a_pf[3] = h1v.y;
            a_pf[4] = h2v.x; a_pf[5] = h2v.y; a_pf[6] = h3v.x; a_pf[7] = h3v.y;
        }
        int kB = kg + lb_k;
        const float* rowp = (kB < Dn) ? (W + (size_t)kB * G4n)
                                      : (U + (size_t)(kB - Dn) * G4n);
        float4 wv = *(const float4*)(rowp + lb_gate * UNITSn + u0 + lb_uoff);
        b_pf[0] = (double)wv.x; b_pf[1] = (double)wv.y;
        b_pf[2] = (double)wv.z; b_pf[3] = (double)wv.w;
    };
    auto store_tiles = [&](int p) {
        double* As = smem + p * 2048;
        double* Bs = smem + 4096 + p * 1024;
        #pragma unroll
        for (int j = 0; j < 8; j++) As[(la_k0 + j) * 64 + la_row] = a_pf[j];
        double2 w0; w0.x = b_pf[0]; w0.y = b_pf[1];
        double2 w1; w1.x = b_pf[2]; w1.y = b_pf[3];
        *(double2*)&Bs[lb_k * 32 + lb_c4] = w0;
        *(double2*)&Bs[lb_k * 32 + lb_c4 + 2] = w1;
    };

    const int lane = tid & 63;
    const int wv_ = tid >> 6;
    const int ri = lane >> 3;
    const int cj = lane & 7;
    const int rb = wv_ * 16 + ri * 2;

    double acc[2][4];
    #pragma unroll
    for (int i = 0; i < 2; i++)
        #pragma unroll
        for (int j = 0; j < 4; j++) acc[i][j] = 0.0;

    prefetch(0);
    store_tiles(0);
    __syncthreads();

    int p = 0;
    for (int it = 0; it < NT; it++) {
        if (it + 1 < NT) prefetch(it + 1);
        {
            const double* As = smem + p * 2048;
            const double* Bs = smem + 4096 + p * 1024;
            #pragma unroll
            for (int k = 0; k < 32; k++) {
                double2 a2 = *(const double2*)&As[k * 64 + rb];
                double2 b0 = *(const double2*)&Bs[k * 32 + cj * 4];
                double2 b1 = *(const double2*)&Bs[k * 32 + cj * 4 + 2];
                acc[0][0] = fma(a2.x, b0.x, acc[0][0]);
                acc[0][1] = fma(a2.x, b0.y, acc[0][1]);
                acc[0][2] = fma(a2.x, b1.x, acc[0][2]);
                acc[0][3] = fma(a2.x, b1.y, acc[0][3]);
                acc[1][0] = fma(a2.y, b0.x, acc[1][0]);
                acc[1][1] = fma(a2.y, b0.y, acc[1][1]);
                acc[1][2] = fma(a2.y, b1.x, acc[1][2]);
                acc[1][3] = fma(a2.y, b1.y, acc[1][3]);
            }
        }
        if (it + 1 < NT) store_tiles(p ^ 1);
        __syncthreads();
        p ^= 1;
    }

    double* zex = smem;
    #pragma unroll
    for (int i = 0; i < 2; i++) {
        double2 z0; z0.x = acc[i][0]; z0.y = acc[i][1];
        double2 z1; z1.x = acc[i][2]; z1.y = acc[i][3];
        *(double2*)&zex[(rb + i) * 32 + cj * 4] = z0;
        *(double2*)&zex[(rb + i) * 32 + cj * 4 + 2] = z1;
    }
    __syncthreads();

    const int eu = tid & 7;
    const int rr = tid >> 3;
    const int ug = u0 + eu;
    const double bi0 = (double)bias[ug];
    const double bf0 = (double)bias[UNITSn + ug];
    const double bc0 = (double)bias[2 * UNITSn + ug];
    const double bo0 = (double)bias[3 * UNITSn + ug];

    #pragma unroll
    for (int s = 0; s < 2; s++) {
        int r = rr + 32 * s;
        int row = rowbase + r;
        double zi = zex[r * 32 + eu]      + bi0;
        double zf = zex[r * 32 + 8 + eu]  + bf0;
        double zc = zex[r * 32 + 16 + eu] + bc0;
        double zo = zex[r * 32 + 24 + eu] + bo0;
        if (t > 0) {
            u64 sp = slots_prev[row];
            int idx = 1023 - (int)(sp & 1023ull);
            const float* wrow = W + (size_t)(Dn + idx) * G4n + ug;
            zi += (double)wrow[0];
            zf += (double)wrow[UNITSn];
            zc += (double)wrow[2 * UNITSn];
            zo += (double)wrow[3 * UNITSn];
            if (ut == 0 && eu == 0) out[(size_t)row * Tn + (t - 1)] = idx;
        }
        size_t off = (size_t)row * UNITSn + ug;
        double cold = cst[off];
        double ig = hsigd(zi), fg = hsigd(zf), og = hsigd(zo);
        double cn = fg * cold + ig * tanh(zc);
        double hn = og * tanh(cn);
        cst[off] = cn;
        hout[off] = hn;
    }
}

#define C_RT 8
#define C_CT 64
#define C_KC 32

__global__ __launch_bounds__(256) void logits_argmax(
    const double* __restrict__ h, const float* __restrict__ Wout,
    const float* __restrict__ bout, u64* __restrict__ slots)
{
    __shared__ double Hs[C_KC][9];
    __shared__ float  Ws[C_KC][C_CT];

    const int tid = threadIdx.x;
    const int ty = tid >> 5;
    const int tx = tid & 31;
    const int rbase = blockIdx.y * C_RT;
    const int cbase = blockIdx.x * C_CT;

    double acc0 = 0.0, acc1 = 0.0;

    const int lh_row = tid >> 5;
    const int lh_kk = tid & 31;
    const int lw_kk = tid >> 4;
    const int lw_j0 = (tid & 15) * 4;

    for (int kb = 0; kb < UNITSn; kb += C_KC) {
        Hs[lh_kk][lh_row] = h[(size_t)(rbase + lh_row) * UNITSn + kb + lh_kk];
        #pragma unroll
        for (int it = 0; it < 2; it++) {
            int kk = lw_kk + it * 16;
            float4 v = *(const float4*)(Wout + (size_t)(kb + kk) * NCn + cbase + lw_j0);
            *(float4*)&Ws[kk][lw_j0] = v;
        }
        __syncthreads();
        #pragma unroll
        for (int kk = 0; kk < C_KC; kk++) {
            double a = Hs[kk][ty];
            float2 wv = *(const float2*)&Ws[kk][tx * 2];
            acc0 = fma(a, (double)wv.x, acc0);
            acc1 = fma(a, (double)wv.y, acc1);
        }
        __syncthreads();
    }

    int col0 = cbase + tx * 2;
    double lg0 = acc0 + (double)bout[col0];
    double lg1 = acc1 + (double)bout[col0 + 1];

    u64 p0 = packlc(lg0, col0);
    u64 p1 = packlc(lg1, col0 + 1);
    u64 best = (p0 > p1) ? p0 : p1;
    #pragma unroll
    for (int off = 16; off >= 1; off >>= 1) {
        u64 o = __shfl_down(best, off, 32);
        if (o > best) best = o;
    }
    if (tx == 0) atomicMax(&slots[rbase + ty], best);
}

__global__ void final_decode(const u64* __restrict__ slots, int* __restrict__ out) {
    int b = threadIdx.x;
    u64 s = slots[b];
    out[(size_t)b * Tn + (Tn - 1)] = 1023 - (int)(s & 1023ull);
}

extern "C" void kernel_launch(void* const* d_in, const int* in_sizes, int n_in,
                              void* d_out, int out_size, void* d_ws, size_t ws_size,
                              hipStream_t stream) {
    const float* x    = (const float*)d_in[0];
    const float* W    = (const float*)d_in[1];
    const float* U    = (const float*)d_in[2];
    const float* bias = (const float*)d_in[3];
    const float* Wout = (const float*)d_in[4];
    const float* bout = (const float*)d_in[5];
    int* out = (int*)d_out;
    char* ws = (char*)d_ws;

    // ws layout: h0 2MB | h1 2MB | c 2MB (fallback) | slots0 @6MB | slots1 @+2048 |
    //            root @+4096 | leaves @+8192 (64 x 16 u64 = 8KB)
    double* h0 = (double*)(ws);
    double* h1 = (double*)(ws + (2u << 20));
    double* c  = (double*)(ws + (4u << 20));
    u64* slots0 = (u64*)(ws + (6u << 20));
    u64* slots1 = (u64*)(ws + (6u << 20) + 2048);
    u64* root   = (u64*)(ws + (6u << 20) + 4096);
    u64* leaves = (u64*)(ws + (6u << 20) + 8192);

    const size_t NEED = (7ull << 20);
    const bool big = ws_size >= NEED;

    hipMemsetAsync(d_ws, 0, (6u << 20) + 16384, stream);

    if (big) {
        lstm_persistent<<<dim3(512), 256, 0, stream>>>(x, W, U, bias, Wout, bout,
                                                       h0, h1, slots0, slots1,
                                                       root, leaves, out);
    } else {
        for (int t = 0; t < Tn; t++) {
            double* hin  = (t & 1) ? h1 : h0;
            double* hout = (t & 1) ? h0 : h1;
            u64* sprev = (t & 1) ? slots0 : slots1;
            u64* scur  = (t & 1) ? slots1 : slots0;
            lstm_step<<<dim3(512), 256, 0, stream>>>(x, W, U, bias, hin, hout, c,
                                                     sprev, scur, out, t);
            logits_argmax<<<dim3(8, 32), 256, 0, stream>>>(hout, Wout, bout, scur);
        }
        final_decode<<<1, Bn, 0, stream>>>(slots1, out);
    }
}